// Round 2
// baseline (197.339 us; speedup 1.0000x reference)
//
#include <hip/hip_runtime.h>
#include <math.h>

#define T_STEPS 1000000
#define BLOCK 256
#define ITEMS 4
#define CHUNK (BLOCK * ITEMS)
#define NB ((T_STEPS + CHUNK - 1) / CHUNK)  // 977

typedef unsigned int uint;

// ---- block helpers (fp64, LDS) ------------------------------------------

__device__ __forceinline__ double blockScanEx(double v, double* s, double* tot) {
    const int t = threadIdx.x;
    s[t] = v;
    __syncthreads();
#pragma unroll
    for (int off = 1; off < BLOCK; off <<= 1) {
        double x = (t >= off) ? s[t - off] : 0.0;
        __syncthreads();
        s[t] += x;
        __syncthreads();
    }
    double ex = (t > 0) ? s[t - 1] : 0.0;
    double T = s[BLOCK - 1];
    __syncthreads();
    *tot = T;
    return ex;
}

__device__ __forceinline__ double blockSum(double v, double* s) {
    const int t = threadIdx.x;
    s[t] = v;
    __syncthreads();
#pragma unroll
    for (int off = BLOCK / 2; off > 0; off >>= 1) {
        if (t < off) s[t] += s[t + off];
        __syncthreads();
    }
    double r = s[0];
    __syncthreads();
    return r;
}

// fast trig: fp64 range reduction -> HW v_sin_f32/v_cos_f32 (abs err ~1e-6)
__device__ __forceinline__ void ftrig(double th, double& cs, double& sn) {
    const double INV2PI = 0.15915494309189535;
    const double TWOPI  = 6.283185307179586;
    double rev = th * INV2PI;
    double f = rev - rint(rev);          // [-0.5, 0.5], exact-ish in fp64
    float x = (float)(f * TWOPI);
    sn = (double)__sinf(x);
    cs = (double)__cosf(x);
}

// ---- init: clear ticket + flags (ws is NOT re-poisoned between replays) --

__global__ void k_init(uint* __restrict__ ticket, uint* __restrict__ flags) {
    int i = blockIdx.x * blockDim.x + threadIdx.x;
    if (i == 0) *ticket = 0;
    if (i < NB) flags[i] = 0;
}

// ---- fused rollout with decoupled lookback -------------------------------

__global__ void __launch_bounds__(BLOCK) k_roll(
    const float2* __restrict__ ctrl, const float* __restrict__ sp,
    float2* __restrict__ ctrl_out, float* __restrict__ traj,
    uint* __restrict__ ticket, uint* __restrict__ flags,
    double* __restrict__ aggTh, double* __restrict__ aggA,
    double* __restrict__ aggB) {
    __shared__ double s0[BLOCK];
    __shared__ double s1[BLOCK];
    __shared__ uint s_tick;
    const int t = threadIdx.x;

    // start-ordered virtual block id: preds are guaranteed running-or-done
    if (t == 0) s_tick = atomicAdd(ticket, 1u);
    __syncthreads();
    const int b = (int)s_tick;
    const long e0 = (long)b * CHUNK + (long)t * ITEMS;

    // -- load controls (blocked: 32B/lane, contiguous across wave) --
    float2 c[ITEMS];
#pragma unroll
    for (int k = 0; k < ITEMS; ++k) {
        long i = e0 + k;
        c[k] = (i < T_STEPS) ? ctrl[i] : make_float2(0.f, 0.f);
    }

    // -- local dtheta scan --
    double dth[ITEMS];
    double lth = 0.0;
#pragma unroll
    for (int k = 0; k < ITEMS; ++k) {
        dth[k] = 10.0 * (double)c[k].y;
        lth += dth[k];
    }
    double thTot;
    double thb = blockScanEx(lth, s0, &thTot);  // local theta before 1st owned elem

    // -- local a,b = s*(cos,sin) of LOCAL angle; their thread sums --
    double av[ITEMS], bv[ITEMS];
    double la = 0.0, lb = 0.0;
    {
        double run = thb;
#pragma unroll
        for (int k = 0; k < ITEMS; ++k) {
            double cs, sn;
            ftrig(run, cs, sn);
            double spd = (e0 + k < T_STEPS) ? fabs((double)c[k].x) : 0.0;
            av[k] = spd * cs;
            bv[k] = spd * sn;
            la += av[k];
            lb += bv[k];
            run += dth[k];
        }
    }
    double aTot, bTot;
    double ab = blockScanEx(la, s0, &aTot);
    double bb = blockScanEx(lb, s1, &bTot);

    // -- publish aggregate ASAP --
    if (t == 0) {
        __hip_atomic_store(&aggTh[b], thTot, __ATOMIC_RELAXED, __HIP_MEMORY_SCOPE_AGENT);
        __hip_atomic_store(&aggA[b], aTot, __ATOMIC_RELAXED, __HIP_MEMORY_SCOPE_AGENT);
        __hip_atomic_store(&aggB[b], bTot, __ATOMIC_RELAXED, __HIP_MEMORY_SCOPE_AGENT);
        __hip_atomic_store(&flags[b], 1u, __ATOMIC_RELEASE, __HIP_MEMORY_SCOPE_AGENT);
    }

    // -- controls copy (overlaps other blocks' lookback waits) --
#pragma unroll
    for (int k = 0; k < ITEMS; ++k) {
        long i = e0 + k;
        if (i < T_STEPS) ctrl_out[i] = c[k];
    }

    // -- lookback: compose ALL predecessor aggregates in parallel --
    const double x0 = (double)sp[0], y0 = (double)sp[1], th0 = (double)sp[2];

#pragma unroll
    for (int k = 0; k < ITEMS; ++k) {
        int p = t * ITEMS + k;  // thread owns contiguous preds (order matters)
        if (p < b) {
            while (__hip_atomic_load(&flags[p], __ATOMIC_RELAXED,
                                     __HIP_MEMORY_SCOPE_AGENT) == 0u)
                __builtin_amdgcn_s_sleep(2);
        }
    }
    __threadfence();  // acquire: aggregates of all seen flags now visible

    double pTh[ITEMS], pA[ITEMS], pB[ITEMS];
    double sth = 0.0;
#pragma unroll
    for (int k = 0; k < ITEMS; ++k) {
        int p = t * ITEMS + k;
        if (p < b) {
            pTh[k] = __hip_atomic_load(&aggTh[p], __ATOMIC_RELAXED, __HIP_MEMORY_SCOPE_AGENT);
            pA[k]  = __hip_atomic_load(&aggA[p], __ATOMIC_RELAXED, __HIP_MEMORY_SCOPE_AGENT);
            pB[k]  = __hip_atomic_load(&aggB[p], __ATOMIC_RELAXED, __HIP_MEMORY_SCOPE_AGENT);
        } else {
            pTh[k] = pA[k] = pB[k] = 0.0;
        }
        sth += pTh[k];
    }

    double thpreTot;
    double thpre = blockScanEx(sth, s0, &thpreTot);  // theta prefix before my preds
    double cx = 0.0, cy = 0.0;
    {
        double run2 = th0 + thpre;  // entry angle of pred p
#pragma unroll
        for (int k = 0; k < ITEMS; ++k) {
            int p = t * ITEMS + k;
            if (p < b) {
                double cs, sn;
                ftrig(run2, cs, sn);
                cx += cs * pA[k] - sn * pB[k];
                cy += sn * pA[k] + cs * pB[k];
                run2 += pTh[k];
            }
        }
    }
    const double Xin = x0 + blockSum(cx, s0);
    const double Yin = y0 + blockSum(cy, s1);
    const double psi = th0 + thpreTot;  // my block's entry angle

    double cps, sps;
    ftrig(psi, cps, sps);

    // -- final per-element outputs --
    {
        double run = thb, Ar = ab, Br = bb;
#pragma unroll
        for (int k = 0; k < ITEMS; ++k) {
            run += dth[k];
            Ar += av[k];
            Br += bv[k];
            long i = e0 + k;
            if (i < T_STEPS) {
                float* row = traj + 3 * (i + 1);
                row[0] = (float)(Xin + cps * Ar - sps * Br);
                row[1] = (float)(Yin + sps * Ar + cps * Br);
                row[2] = (float)(psi + run);
            }
        }
    }
    if (blockIdx.x == 0 && t == 0) {
        traj[0] = sp[0];
        traj[1] = sp[1];
        traj[2] = sp[2];
    }
}

// ---- launch --------------------------------------------------------------

extern "C" void kernel_launch(void* const* d_in, const int* in_sizes, int n_in,
                              void* d_out, int out_size, void* d_ws, size_t ws_size,
                              hipStream_t stream) {
    const float*  start_pose = (const float*)d_in[0];
    const float2* ctrl       = (const float2*)d_in[1];

    float*  out      = (float*)d_out;
    float2* ctrl_out = (float2*)out;
    float*  traj     = out + 2 * (long)T_STEPS;

    char* ws = (char*)d_ws;
    uint*   ticket = (uint*)ws;                       // 0
    double* aggTh  = (double*)(ws + 64);              // 64 .. +7816
    double* aggA   = aggTh + NB;
    double* aggB   = aggA + NB;
    uint*   flags  = (uint*)(ws + 64 + 3 * NB * 8);   // 4B-aligned

    hipLaunchKernelGGL(k_init, dim3((NB + BLOCK - 1) / BLOCK), dim3(BLOCK), 0, stream,
                       ticket, flags);
    hipLaunchKernelGGL(k_roll, dim3(NB), dim3(BLOCK), 0, stream,
                       ctrl, start_pose, ctrl_out, traj,
                       ticket, flags, aggTh, aggA, aggB);
}

// Round 3
// 23.465 us; speedup vs baseline: 8.4101x; 8.4101x over previous
//
#include <hip/hip_runtime.h>
#include <math.h>

#define T_STEPS 1000000
#define BLOCK 256
#define ITEMS 8
#define CHUNK (BLOCK * ITEMS)               // 2048
#define NB ((T_STEPS + CHUNK - 1) / CHUNK)  // 489
#define NF4 (T_STEPS / 2)                   // 500000 float4 of controls
#define PER 2                               // aggregates per thread in compose (489 <= 512)

// ---- wave/block scan helpers (fp64, shfl-based, 1 barrier each) ---------

__device__ __forceinline__ double waveScanIncl(double v) {
#pragma unroll
    for (int off = 1; off < 64; off <<= 1) {
        double x = __shfl_up(v, off, 64);
        if ((threadIdx.x & 63) >= off) v += x;
    }
    return v;
}

// exclusive prefix over the block's per-thread values; *tot = block total
__device__ __forceinline__ double blockScanEx(double v, double* sw, double* tot) {
    const int lane = threadIdx.x & 63, w = threadIdx.x >> 6;
    double inc = waveScanIncl(v);
    if (lane == 63) sw[w] = inc;
    __syncthreads();
    double w0 = sw[0], w1 = sw[1], w2 = sw[2], w3 = sw[3];
    __syncthreads();
    *tot = w0 + w1 + w2 + w3;
    double woff = (w > 0 ? w0 : 0.0) + (w > 1 ? w1 : 0.0) + (w > 2 ? w2 : 0.0);
    return woff + inc - v;
}

__device__ __forceinline__ double blockSum(double v, double* sw) {
#pragma unroll
    for (int off = 32; off > 0; off >>= 1) v += __shfl_xor(v, off, 64);
    const int lane = threadIdx.x & 63, w = threadIdx.x >> 6;
    if (lane == 0) sw[w] = v;
    __syncthreads();
    double r = sw[0] + sw[1] + sw[2] + sw[3];
    __syncthreads();
    return r;
}

// fp64 range reduction -> HW v_sin_f32/v_cos_f32 (abs err ~1e-6)
__device__ __forceinline__ void ftrig(double th, double& cs, double& sn) {
    const double INV2PI = 0.15915494309189535;
    double rev = th * INV2PI;
    double fr = rev - rint(rev);                 // [-0.5, 0.5]
    float x = (float)fr * 6.283185307179586f;
    sn = (double)__sinf(x);
    cs = (double)__cosf(x);
}

// ---- K1: controls copy + per-block rigid-motion aggregates --------------
// Aggregate of block p (entry angle unknown): Theta = sum dth,
// A = sum s*cos(phi_local), B = sum s*sin(phi_local).

__global__ void __launch_bounds__(BLOCK) k_agg(
    const float4* __restrict__ ctrl4, float4* __restrict__ out4,
    double* __restrict__ aggTh, double* __restrict__ aggA,
    double* __restrict__ aggB) {
    __shared__ double sw[4];
    const int b = blockIdx.x, t = threadIdx.x;
    const int f0 = b * (CHUNK / 2) + t * (ITEMS / 2);

    float4 c4[ITEMS / 2];
#pragma unroll
    for (int j = 0; j < ITEMS / 2; ++j) {
        int f = f0 + j;
        c4[j] = (f < NF4) ? ctrl4[f] : make_float4(0.f, 0.f, 0.f, 0.f);
    }
#pragma unroll
    for (int j = 0; j < ITEMS / 2; ++j) {
        int f = f0 + j;
        if (f < NF4) out4[f] = c4[j];  // controls passthrough output
    }

    double dth[ITEMS];
    double lth = 0.0;
#pragma unroll
    for (int j = 0; j < ITEMS / 2; ++j) {
        dth[2 * j]     = 10.0 * (double)c4[j].y;
        dth[2 * j + 1] = 10.0 * (double)c4[j].w;
        lth += dth[2 * j] + dth[2 * j + 1];
    }
    double thTot;
    double thb = blockScanEx(lth, sw, &thTot);  // local angle before 1st owned elem

    double la = 0.0, lb = 0.0;
    {
        double run = thb;
#pragma unroll
        for (int j = 0; j < ITEMS / 2; ++j) {
            double s0 = fabs((double)c4[j].x);
            double s1 = fabs((double)c4[j].z);
            double cs, sn;
            ftrig(run, cs, sn);
            la += s0 * cs; lb += s0 * sn;
            run += dth[2 * j];
            ftrig(run, cs, sn);
            la += s1 * cs; lb += s1 * sn;
            run += dth[2 * j + 1];
        }
    }
    double A = blockSum(la, sw);
    double B = blockSum(lb, sw);
    if (t == 0) {
        aggTh[b] = thTot;
        aggA[b]  = A;
        aggB[b]  = B;
    }
}

// ---- K2: compose aggregates, redo local scan, write traj ----------------

__global__ void __launch_bounds__(BLOCK) k_out(
    const float4* __restrict__ ctrl4, const float* __restrict__ sp,
    const double* __restrict__ aggTh, const double* __restrict__ aggA,
    const double* __restrict__ aggB, float* __restrict__ traj) {
    __shared__ double sw[4];
    const int b = blockIdx.x, t = threadIdx.x;

    const double x0 = (double)sp[0], y0 = (double)sp[1], th0 = (double)sp[2];

    // -- phase 1: entry state (Xin, Yin, psi) from predecessor aggregates --
    double pTh[PER], pA[PER], pB[PER];
    double lsum = 0.0;
#pragma unroll
    for (int k = 0; k < PER; ++k) {
        int p = t * PER + k;
        if (p < NB) {
            pTh[k] = aggTh[p];
            pA[k]  = aggA[p];
            pB[k]  = aggB[p];
        } else {
            pTh[k] = pA[k] = pB[k] = 0.0;
        }
        lsum += pTh[k];
    }
    double dummyTot;
    double excl = blockScanEx(lsum, sw, &dummyTot);  // theta prefix before my slots

    double cx = 0.0, cy = 0.0, mth = 0.0;
    {
        double run = th0 + excl;  // entry angle of aggregate p
#pragma unroll
        for (int k = 0; k < PER; ++k) {
            int p = t * PER + k;
            if (p < b) {
                double cs, sn;
                ftrig(run, cs, sn);
                cx += cs * pA[k] - sn * pB[k];
                cy += sn * pA[k] + cs * pB[k];
                mth += pTh[k];
            }
            run += pTh[k];
        }
    }
    const double psi = th0 + blockSum(mth, sw);  // my block's entry angle
    const double Xin = x0 + blockSum(cx, sw);
    const double Yin = y0 + blockSum(cy, sw);
    double cps, sps;
    ftrig(psi, cps, sps);

    // -- phase 2: local scan (same as K1) + final writes --
    const int f0 = b * (CHUNK / 2) + t * (ITEMS / 2);
    float4 c4[ITEMS / 2];
#pragma unroll
    for (int j = 0; j < ITEMS / 2; ++j) {
        int f = f0 + j;
        c4[j] = (f < NF4) ? ctrl4[f] : make_float4(0.f, 0.f, 0.f, 0.f);
    }
    double dth[ITEMS];
    double lth = 0.0;
#pragma unroll
    for (int j = 0; j < ITEMS / 2; ++j) {
        dth[2 * j]     = 10.0 * (double)c4[j].y;
        dth[2 * j + 1] = 10.0 * (double)c4[j].w;
        lth += dth[2 * j] + dth[2 * j + 1];
    }
    double thTot;
    double thb = blockScanEx(lth, sw, &thTot);

    double av[ITEMS], bv[ITEMS];
    double la = 0.0, lb = 0.0;
    {
        double run = thb;
#pragma unroll
        for (int j = 0; j < ITEMS / 2; ++j) {
            double s0 = fabs((double)c4[j].x);
            double s1 = fabs((double)c4[j].z);
            double cs, sn;
            ftrig(run, cs, sn);
            av[2 * j] = s0 * cs; bv[2 * j] = s0 * sn;
            run += dth[2 * j];
            ftrig(run, cs, sn);
            av[2 * j + 1] = s1 * cs; bv[2 * j + 1] = s1 * sn;
            run += dth[2 * j + 1];
            la += av[2 * j] + av[2 * j + 1];
            lb += bv[2 * j] + bv[2 * j + 1];
        }
    }
    double aTot, bTot;
    double Ar = blockScanEx(la, sw, &aTot);
    double Br = blockScanEx(lb, sw, &bTot);

    {
        const long e0 = (long)b * CHUNK + (long)t * ITEMS;
        double run = thb;
#pragma unroll
        for (int k = 0; k < ITEMS; ++k) {
            Ar += av[k];
            Br += bv[k];
            run += dth[k];
            long i = e0 + k;
            if (i < T_STEPS) {
                float* row = traj + 3 * (i + 1);
                row[0] = (float)(Xin + cps * Ar - sps * Br);
                row[1] = (float)(Yin + sps * Ar + cps * Br);
                row[2] = (float)(psi + run);
            }
        }
    }
    if (b == 0 && t == 0) {
        traj[0] = sp[0];
        traj[1] = sp[1];
        traj[2] = sp[2];
    }
}

// ---- launch --------------------------------------------------------------

extern "C" void kernel_launch(void* const* d_in, const int* in_sizes, int n_in,
                              void* d_out, int out_size, void* d_ws, size_t ws_size,
                              hipStream_t stream) {
    const float*  start_pose = (const float*)d_in[0];
    const float4* ctrl4      = (const float4*)d_in[1];

    float*  out  = (float*)d_out;
    float4* out4 = (float4*)out;                 // controls passthrough
    float*  traj = out + 2 * (long)T_STEPS;      // (T+1, 3)

    double* bsum  = (double*)d_ws;
    double* aggTh = bsum;
    double* aggA  = aggTh + NB;
    double* aggB  = aggA + NB;

    hipLaunchKernelGGL(k_agg, dim3(NB), dim3(BLOCK), 0, stream,
                       ctrl4, out4, aggTh, aggA, aggB);
    hipLaunchKernelGGL(k_out, dim3(NB), dim3(BLOCK), 0, stream,
                       ctrl4, start_pose, aggTh, aggA, aggB, traj);
}